// Round 1
// baseline (1822.484 us; speedup 1.0000x reference)
//
#include <hip/hip_runtime.h>
#include <math.h>

// Problem constants (from reference)
#define Bc 8
#define Sc 4
#define Nc 64
#define AF 133
#define BFD 147
#define Hc 300
#define BS (Bc*Sc)                  // 32
#define ROWS (BS*Nc)                // 2048 atom rows
#define EDGES (BS*Nc*Nc)            // 131072 edges
#define PAIRS_PER_BS ((Nc*(Nc+1))/2)   // 2080
#define TOTAL_PAIRS (BS*PAIRS_PER_BS)  // 66560

__device__ __forceinline__ float reluf(float x){ return fmaxf(x, 0.f); }

// ---------------- K1: input_atom = relu(f_atoms @ W_i_atom); message_atom = copy
__global__ __launch_bounds__(320) void k_atom_embed(const float* __restrict__ f_atoms,
        const float* __restrict__ W, float* __restrict__ input_atom, float* __restrict__ message_atom){
    __shared__ float x[AF];
    int row = blockIdx.x;
    const float* fr = f_atoms + (size_t)row*AF;
    for (int d = threadIdx.x; d < AF; d += blockDim.x) x[d] = fr[d];
    __syncthreads();
    int h = threadIdx.x;
    if (h < Hc){
        float acc = 0.f;
        for (int d = 0; d < AF; ++d) acc = fmaf(x[d], W[d*Hc + h], acc);
        float v = reluf(acc);
        input_atom[(size_t)row*Hc + h] = v;
        message_atom[(size_t)row*Hc + h] = v;
    }
}

// ---------------- K2: input_bond = relu((adj*f_bonds) @ W_i_bond); message_bond = copy
#define E2 8
__global__ __launch_bounds__(320) void k_bond_embed(const float* __restrict__ f_bonds,
        const float* __restrict__ adj, const float* __restrict__ W,
        float* __restrict__ input_bond, float* __restrict__ message_bond){
    __shared__ float x[E2][BFD];
    int e0 = blockIdx.x * E2;
    for (int idx = threadIdx.x; idx < E2*BFD; idx += blockDim.x){
        int e = idx / BFD, d = idx - e*BFD;
        int edge = e0 + e;
        float a = adj[edge];
        x[e][d] = a * f_bonds[(size_t)edge*BFD + d];
    }
    __syncthreads();
    int h = threadIdx.x;
    if (h < Hc){
        float acc[E2];
        #pragma unroll
        for (int e=0;e<E2;e++) acc[e]=0.f;
        for (int d = 0; d < BFD; ++d){
            float w = W[d*Hc + h];
            #pragma unroll
            for (int e=0;e<E2;e++) acc[e] = fmaf(x[e][d], w, acc[e]);
        }
        #pragma unroll
        for (int e=0;e<E2;e++){
            float v = reluf(acc[e]);
            size_t off = (size_t)(e0+e)*Hc + h;
            input_bond[off] = v;
            message_bond[off] = v;
        }
    }
}

// ---------------- K3: agg[b,s,m,h] = sum_n mb[b,s,n,m,h] * sigmoid(max_n mb[b,s,n,m,h])
// final_mode=0: message_atom += agg ; final_mode=1: agg_out = agg (message_atom untouched)
__global__ __launch_bounds__(320) void k_agg(const float* __restrict__ message_bond,
        float* __restrict__ message_atom, float* __restrict__ agg_out, int final_mode){
    int row = blockIdx.x;           // bs*64 + m
    int bs = row >> 6, m = row & 63;
    int h = threadIdx.x;
    if (h >= Hc) return;
    size_t base = ((size_t)(bs*Nc)*Nc + m)*(size_t)Hc + h;
    float s = 0.f, mx = -INFINITY;
    for (int n = 0; n < Nc; ++n){
        float v = message_bond[base + (size_t)n*Nc*Hc];
        s += v; mx = fmaxf(mx, v);
    }
    float sig = 1.f/(1.f + expf(-mx));
    float agg = s * sig;
    if (final_mode) agg_out[(size_t)row*Hc + h] = agg;
    else message_atom[(size_t)row*Hc + h] += agg;
}

// ---------------- K4: res[n,m] = dot(ma[n],ma[m])*adj[n,m]; sm = softmax over n (per b,s,m column)
__global__ __launch_bounds__(256) void k_resonance_softmax(const float* __restrict__ message_atom,
        const float* __restrict__ adj, float* __restrict__ sm){
    int bs = blockIdx.x >> 6, m = blockIdx.x & 63;
    __shared__ float am[Hc];
    __shared__ float res[Nc];
    for (int d = threadIdx.x; d < Hc; d += blockDim.x)
        am[d] = message_atom[((size_t)(bs*Nc)+m)*Hc + d];
    __syncthreads();
    int wave = threadIdx.x >> 6, lane = threadIdx.x & 63;
    for (int n = wave; n < Nc; n += 4){
        const float* man = message_atom + ((size_t)(bs*Nc)+n)*Hc;
        float acc = 0.f;
        for (int d = lane; d < Hc; d += 64) acc = fmaf(man[d], am[d], acc);
        #pragma unroll
        for (int off = 32; off > 0; off >>= 1) acc += __shfl_xor(acc, off, 64);
        if (lane == 0) res[n] = acc * adj[((size_t)(bs*Nc)+n)*Nc + m];
    }
    __syncthreads();
    if (threadIdx.x < Nc){
        float v = res[threadIdx.x];
        float mx = v;
        #pragma unroll
        for (int off = 32; off > 0; off >>= 1) mx = fmaxf(mx, __shfl_xor(mx, off, 64));
        float e = expf(v - mx);
        float ssum = e;
        #pragma unroll
        for (int off = 32; off > 0; off >>= 1) ssum += __shfl_xor(ssum, off, 64);
        sm[((size_t)(bs*Nc)+threadIdx.x)*Nc + m] = e / ssum;
    }
}

// ---------------- K5: in-place pair update of message_bond
// mb_new[n,m,h] = relu(input_bond[n,m,h] + sum_d (adj[m,n]*ma[n,d] - mb_old[m,n,d]) * W_h[d,h]) * sm[n,m]
// Each block owns PPB unordered pairs {n,m}: reads both directions into LDS, syncs, writes both.
#define PPB 4
#define ES (2*PPB)
__global__ __launch_bounds__(320) void k_pair_update(
        const float* __restrict__ W_h, const float* __restrict__ input_bond,
        const float* __restrict__ message_atom, const float* __restrict__ adj,
        const float* __restrict__ sm, float* __restrict__ message_bond){
    __shared__ float xs[Hc][ES];         // [d][e] so compute loop reads float4-contiguous
    __shared__ int s_edge[ES], s_src[ES], s_valid[ES];
    if (threadIdx.x < PPB){
        int gp = blockIdx.x*PPB + threadIdx.x;
        int va = 0, vb = 0, e1 = 0, e2 = 0, n = 0, m = 0, bs = 0;
        if (gp < TOTAL_PAIRS){
            bs = gp / PAIRS_PER_BS;
            int p = gp - bs*PAIRS_PER_BS;
            n = (int)floorf((129.f - sqrtf(16641.f - 8.f*(float)p)) * 0.5f);
            if (n < 0) n = 0; if (n > 63) n = 63;
            while (n < 63 && (((n+1)*(129-(n+1)))>>1) <= p) n++;
            while (n > 0 && ((n*(129-n))>>1) > p) n--;
            m = n + (p - ((n*(129-n))>>1));
            e1 = (bs*Nc + n)*Nc + m;
            e2 = (bs*Nc + m)*Nc + n;
            va = 1; vb = (n != m) ? 1 : 0;
        }
        int a = 2*threadIdx.x, b = a+1;
        s_edge[a] = e1; s_src[a] = bs*Nc + n; s_valid[a] = va;
        s_edge[b] = e2; s_src[b] = bs*Nc + m; s_valid[b] = vb;
    }
    __syncthreads();
    for (int idx = threadIdx.x; idx < ES*Hc; idx += blockDim.x){
        int e = idx / Hc, d = idx - e*Hc;
        float v = 0.f;
        if (s_valid[e]){
            int rev = s_edge[e ^ 1];
            float at = adj[rev];
            v = at * message_atom[(size_t)s_src[e]*Hc + d] - message_bond[(size_t)rev*Hc + d];
        }
        xs[d][e] = v;
    }
    __syncthreads();
    int h = threadIdx.x;
    if (h < Hc){
        float acc[ES];
        #pragma unroll
        for (int e=0;e<ES;e++) acc[e]=0.f;
        for (int d = 0; d < Hc; ++d){
            float w = W_h[d*Hc + h];
            const float4* p4 = (const float4*)&xs[d][0];
            float4 xa = p4[0], xb = p4[1];
            acc[0] = fmaf(xa.x, w, acc[0]); acc[1] = fmaf(xa.y, w, acc[1]);
            acc[2] = fmaf(xa.z, w, acc[2]); acc[3] = fmaf(xa.w, w, acc[3]);
            acc[4] = fmaf(xb.x, w, acc[4]); acc[5] = fmaf(xb.y, w, acc[5]);
            acc[6] = fmaf(xb.z, w, acc[6]); acc[7] = fmaf(xb.w, w, acc[7]);
        }
        #pragma unroll
        for (int e=0;e<ES;e++){
            if (s_valid[e]){
                size_t off = (size_t)s_edge[e]*Hc + h;
                float v = reluf(input_bond[off] + acc[e]) * sm[s_edge[e]];
                message_bond[off] = v;
            }
        }
    }
}

// ---------------- K6: atom_hiddens = relu([agg|message_atom|input_atom] @ W_o + b_o)
#define R7 4
__global__ __launch_bounds__(320) void k_output(const float* __restrict__ agg,
        const float* __restrict__ message_atom, const float* __restrict__ input_atom,
        const float* __restrict__ W_o, const float* __restrict__ b_o, float* __restrict__ out){
    __shared__ float xin[R7][3*Hc];
    int r0 = blockIdx.x * R7;
    for (int idx = threadIdx.x; idx < R7*3*Hc; idx += blockDim.x){
        int r = idx / (3*Hc), k = idx - r*(3*Hc);
        int row = r0 + r;
        float v;
        if (k < Hc)           v = agg[(size_t)row*Hc + k];
        else if (k < 2*Hc)    v = message_atom[(size_t)row*Hc + (k - Hc)];
        else                  v = input_atom[(size_t)row*Hc + (k - 2*Hc)];
        xin[r][k] = v;
    }
    __syncthreads();
    int h = threadIdx.x;
    if (h < Hc){
        float acc[R7];
        #pragma unroll
        for (int r=0;r<R7;r++) acc[r] = b_o[h];
        for (int d = 0; d < 3*Hc; ++d){
            float w = W_o[d*Hc + h];
            #pragma unroll
            for (int r=0;r<R7;r++) acc[r] = fmaf(xin[r][d], w, acc[r]);
        }
        #pragma unroll
        for (int r=0;r<R7;r++) out[(size_t)(r0+r)*Hc + h] = reluf(acc[r]);
    }
}

extern "C" void kernel_launch(void* const* d_in, const int* in_sizes, int n_in,
                              void* d_out, int out_size, void* d_ws, size_t ws_size,
                              hipStream_t stream){
    const float* f_atoms  = (const float*)d_in[0];
    const float* f_bonds  = (const float*)d_in[1];
    const float* adj      = (const float*)d_in[2];
    const float* W_i_atom = (const float*)d_in[3];
    const float* W_i_bond = (const float*)d_in[4];
    const float* W_h0     = (const float*)d_in[5];
    const float* W_h1     = (const float*)d_in[6];
    const float* W_o      = (const float*)d_in[7];
    const float* b_o      = (const float*)d_in[8];

    float* out = (float*)d_out;
    float* atom_hiddens = out;                                // [ROWS, Hc]
    float* message_bond = out + (size_t)ROWS*Hc;              // [EDGES, Hc] (output #2, updated in place)

    float* ws = (float*)d_ws;
    float* input_bond   = ws;  ws += (size_t)EDGES*Hc;        // 39.3M floats
    float* input_atom   = ws;  ws += (size_t)ROWS*Hc;
    float* message_atom = ws;  ws += (size_t)ROWS*Hc;
    float* agg_out      = ws;  ws += (size_t)ROWS*Hc;
    float* sm           = ws;  ws += (size_t)EDGES;

    k_atom_embed<<<ROWS, 320, 0, stream>>>(f_atoms, W_i_atom, input_atom, message_atom);
    k_bond_embed<<<EDGES/E2, 320, 0, stream>>>(f_bonds, adj, W_i_bond, input_bond, message_bond);

    const float* Whs[2] = {W_h0, W_h1};
    for (int step = 0; step < 2; ++step){
        k_agg<<<ROWS, 320, 0, stream>>>(message_bond, message_atom, agg_out, 0);
        k_resonance_softmax<<<ROWS, 256, 0, stream>>>(message_atom, adj, sm);
        int nblk = (TOTAL_PAIRS + PPB - 1)/PPB;
        k_pair_update<<<nblk, 320, 0, stream>>>(Whs[step], input_bond, message_atom, adj, sm, message_bond);
    }
    k_agg<<<ROWS, 320, 0, stream>>>(message_bond, message_atom, agg_out, 1);
    k_output<<<ROWS/R7, 320, 0, stream>>>(agg_out, message_atom, input_atom, W_o, b_o, atom_hiddens);
}

// Round 3
// 1552.937 us; speedup vs baseline: 1.1736x; 1.1736x over previous
//
#include <hip/hip_runtime.h>
#include <hip/hip_bf16.h>
#include <math.h>

#define Bc 8
#define Sc 4
#define Nc 64
#define AF 133
#define BFD 147
#define Hc 300
#define BS (Bc*Sc)                  // 32
#define ROWS (BS*Nc)                // 2048 atom rows
#define EDGES (BS*Nc*Nc)            // 131072 edges

typedef float f32x4 __attribute__((ext_vector_type(4)));
typedef short bf16x8 __attribute__((ext_vector_type(8)));
union U4 { uint4 u; bf16x8 v; };

__device__ __forceinline__ float reluf(float x){ return fmaxf(x, 0.f); }
__device__ __forceinline__ float b2f(unsigned short u){ union{unsigned int i;float f;}v; v.i = ((unsigned int)u)<<16; return v.f; }
__device__ __forceinline__ unsigned short f2b(float f){ __hip_bfloat16 h = __float2bfloat16(f); return *reinterpret_cast<unsigned short*>(&h); }
__device__ __forceinline__ void split2(float x, unsigned short &hi, unsigned short &lo){
    unsigned short h = f2b(x);
    float r = x - b2f(h);
    hi = h; lo = f2b(r);
}

// ---------------- K1: input_atom = relu(f_atoms @ W_i_atom); message_atom = copy (fp32 VALU)
__global__ __launch_bounds__(320) void k_atom_embed(const float* __restrict__ f_atoms,
        const float* __restrict__ W, float* __restrict__ input_atom, float* __restrict__ message_atom){
    __shared__ float x[AF];
    int row = blockIdx.x;
    const float* fr = f_atoms + (size_t)row*AF;
    for (int d = threadIdx.x; d < AF; d += blockDim.x) x[d] = fr[d];
    __syncthreads();
    int h = threadIdx.x;
    if (h < Hc){
        float acc = 0.f;
        for (int d = 0; d < AF; ++d) acc = fmaf(x[d], W[d*Hc + h], acc);
        float v = reluf(acc);
        input_atom[(size_t)row*Hc + h] = v;
        message_atom[(size_t)row*Hc + h] = v;
    }
}

// ---------------- prep: split-transpose W -> Whi/Wlo [304][KPAD] bf16 (k-inner), zero-padded
__global__ __launch_bounds__(256) void k_prep_w(const float* __restrict__ W, int K, int KPAD,
        unsigned short* __restrict__ Whi, unsigned short* __restrict__ Wlo){
    int idx = blockIdx.x*256 + threadIdx.x;
    if (idx >= 304*KPAD) return;
    int h = idx / KPAD, k = idx - h*KPAD;
    float v = (h < Hc && k < K) ? W[k*Hc + h] : 0.f;
    unsigned short hi, lo; split2(v, hi, lo);
    Whi[idx] = hi; Wlo[idx] = lo;
}

// ---------------- prep: X2[e][k] = adj[e]*f_bonds[e][k] fp32, zero-padded to K=160
__global__ __launch_bounds__(256) void k_bond_prep(const float* __restrict__ f_bonds,
        const float* __restrict__ adj, float* __restrict__ X2){
    int idx = blockIdx.x*256 + threadIdx.x;   // over EDGES*160 (exact multiple of 256)
    int e = idx / 160, k = idx - e*160;
    X2[idx] = (k < BFD) ? adj[e]*f_bonds[(size_t)e*BFD + k] : 0.f;
}

// ---------------- split-bf16 (Ozaki 3-term) MFMA edge GEMM, fp32 in / fp32 out.
// MODE 0: dst = relu(X2 @ W_i_bond)                        (128 rows/block, plain row blocks)
// MODE 1: dst[eo] = relu(ib[eo] + A @ W_h) * sm[eo]        (128 rows/block, closed-pair blocks)
//         A-row for output edge (a,b): adj[(b,a)]*ma[a,:] - mb_old[(b,a),:]
// MODE 1 is in-place-safe: a block's A-read set == its own write set; one barrier separates them.
template<int MODE>
__global__ __launch_bounds__(512) void k_gemm3(
        const float* __restrict__ Asrc,          // MODE0: X2 [E][160]; MODE1: mb_old [E][300]
        const unsigned short* __restrict__ Whi,  // [304][KPAD]
        const unsigned short* __restrict__ Wlo,
        const float* __restrict__ ma,
        const float* __restrict__ adj,
        const float* __restrict__ sm,
        const float* __restrict__ ib,
        float* __restrict__ dst)
{
    constexpr int KPAD = MODE ? 320 : 160;
    constexpr int NKT  = MODE ? 10 : 5;
    constexpr int ASTR = MODE ? 300 : 160;
    const int lane = threadIdx.x & 63, wave = threadIdx.x >> 6;
    const int quad = lane >> 4, li = lane & 15;

    __shared__ int s_eOut[128];
    __shared__ int s_eRev[128];
    __shared__ int s_aAtom[128];
    __shared__ float s_adjRev[128];

    if (MODE){
        if (threadIdx.x < 128){
            int r = threadIdx.x;
            int bs = blockIdx.x >> 5, kk = blockIdx.x & 31;
            int s1 = 64-kk, s2 = 127-2*kk, s3 = 128-kk;
            int a, b;
            if (r < s1){ a = kk; b = kk + r; }
            else if (r < s2){ a = kk+1 + (r - s1); b = kk; }
            else if (r < s3){ a = 63-kk; b = 63-kk + (r - s2); }
            else { a = 64-kk + (r - s3); b = 63-kk; }
            int eo = (bs*64 + a)*64 + b;
            int er = (bs*64 + b)*64 + a;
            s_eOut[r] = eo; s_eRev[r] = er; s_aAtom[r] = bs*64 + a;
            s_adjRev[r] = adj[er];
        }
        __syncthreads();
    }

    const int arow = wave*16 + li;
    int er; int aAtom = 0; float adjR = 0.f;
    if (MODE){ er = s_eRev[arow]; aAtom = s_aAtom[arow]; adjR = s_adjRev[arow]; }
    else       er = blockIdx.x*128 + arow;

    f32x4 acc[19];
    #pragma unroll
    for (int c = 0; c < 19; ++c) acc[c] = (f32x4){0.f,0.f,0.f,0.f};

    const float* aBase = Asrc + (size_t)er*ASTR;
    const float* mBase = MODE ? (ma + (size_t)aAtom*Hc) : nullptr;

    for (int kt = 0; kt < NKT; ++kt){
        const int k0 = kt*32 + quad*8;
        float xv[8];
        if (!MODE){
            float4 a0 = *(const float4*)(aBase + k0);
            float4 a1 = *(const float4*)(aBase + k0 + 4);
            xv[0]=a0.x; xv[1]=a0.y; xv[2]=a0.z; xv[3]=a0.w;
            xv[4]=a1.x; xv[5]=a1.y; xv[6]=a1.z; xv[7]=a1.w;
        } else if (kt < 9){                       // k0+7 <= 287 < 300: unguarded
            float4 m0 = *(const float4*)(mBase + k0);
            float4 m1 = *(const float4*)(mBase + k0 + 4);
            float4 b0 = *(const float4*)(aBase + k0);
            float4 b1 = *(const float4*)(aBase + k0 + 4);
            xv[0]=fmaf(adjR,m0.x,-b0.x); xv[1]=fmaf(adjR,m0.y,-b0.y);
            xv[2]=fmaf(adjR,m0.z,-b0.z); xv[3]=fmaf(adjR,m0.w,-b0.w);
            xv[4]=fmaf(adjR,m1.x,-b1.x); xv[5]=fmaf(adjR,m1.y,-b1.y);
            xv[6]=fmaf(adjR,m1.z,-b1.z); xv[7]=fmaf(adjR,m1.w,-b1.w);
        } else {                                  // last k-tile: guard k >= 300 (no over-read)
            #pragma unroll
            for (int j = 0; j < 8; ++j){
                int kk = k0 + j;
                xv[j] = (kk < Hc) ? fmaf(adjR, mBase[kk], -aBase[kk]) : 0.f;
            }
        }
        // split fp32 -> hi/lo bf16, pack into MFMA fragments
        unsigned int hw[4], lw[4];
        #pragma unroll
        for (int p = 0; p < 4; ++p){
            unsigned short h0, l0, h1, l1;
            split2(xv[2*p],   h0, l0);
            split2(xv[2*p+1], h1, l1);
            hw[p] = (unsigned int)h0 | ((unsigned int)h1 << 16);
            lw[p] = (unsigned int)l0 | ((unsigned int)l1 << 16);
        }
        U4 Ahi, Alo;
        Ahi.u = make_uint4(hw[0],hw[1],hw[2],hw[3]);
        Alo.u = make_uint4(lw[0],lw[1],lw[2],lw[3]);

        const unsigned short* wh = Whi + k0;
        const unsigned short* wl = Wlo + k0;
        #pragma unroll
        for (int c = 0; c < 19; ++c){
            int col = c*16 + li;
            U4 bh, bl;
            bh.u = *(const uint4*)(wh + (size_t)col*KPAD);
            bl.u = *(const uint4*)(wl + (size_t)col*KPAD);
            acc[c] = __builtin_amdgcn_mfma_f32_16x16x32_bf16(Ahi.v, bl.v, acc[c], 0,0,0);
            acc[c] = __builtin_amdgcn_mfma_f32_16x16x32_bf16(Alo.v, bh.v, acc[c], 0,0,0);
            acc[c] = __builtin_amdgcn_mfma_f32_16x16x32_bf16(Ahi.v, bh.v, acc[c], 0,0,0);
        }
    }

    __syncthreads();   // in-place safety: all old-mb reads complete before any write

    int orow[4]; float smv[4] = {0,0,0,0};
    #pragma unroll
    for (int r = 0; r < 4; ++r){
        int row = wave*16 + quad*4 + r;
        int eo = MODE ? s_eOut[row] : blockIdx.x*128 + row;
        orow[r] = eo;
        if (MODE) smv[r] = sm[eo];
    }
    #pragma unroll
    for (int c = 0; c < 19; ++c){
        int h = c*16 + li;
        if (h < Hc){
            #pragma unroll
            for (int r = 0; r < 4; ++r){
                size_t off = (size_t)orow[r]*Hc + h;
                float v = acc[c][r];
                if (MODE) v = reluf(v + ib[off]) * smv[r];
                else      v = reluf(v);
                dst[off] = v;
            }
        }
    }
}

// ---------------- K3: agg[bs,m,h] = (sum_n mb[n,m,h]) * sigmoid(max_n mb[n,m,h])  (fp32)
__global__ __launch_bounds__(320) void k_agg(const float* __restrict__ message_bond,
        float* __restrict__ message_atom, float* __restrict__ agg_out, int final_mode){
    int row = blockIdx.x;           // bs*64 + m
    int bs = row >> 6, m = row & 63;
    int h = threadIdx.x;
    if (h >= Hc) return;
    size_t base = ((size_t)(bs*Nc)*Nc + m)*(size_t)Hc + h;
    float s = 0.f, mx = -INFINITY;
    for (int n = 0; n < Nc; ++n){
        float v = message_bond[base + (size_t)n*Nc*Hc];
        s += v; mx = fmaxf(mx, v);
    }
    float agg = s * (1.f/(1.f + expf(-mx)));
    if (final_mode) agg_out[(size_t)row*Hc + h] = agg;
    else message_atom[(size_t)row*Hc + h] += agg;
}

// ---------------- K4: res[n,m] = dot(ma[n],ma[m])*adj[n,m]; sm = softmax over n per (b,s,m)
__global__ __launch_bounds__(256) void k_resonance_softmax(const float* __restrict__ message_atom,
        const float* __restrict__ adj, float* __restrict__ sm){
    int bs = blockIdx.x >> 6, m = blockIdx.x & 63;
    __shared__ float am[Hc];
    __shared__ float res[Nc];
    for (int d = threadIdx.x; d < Hc; d += blockDim.x)
        am[d] = message_atom[((size_t)(bs*Nc)+m)*Hc + d];
    __syncthreads();
    int wave = threadIdx.x >> 6, lane = threadIdx.x & 63;
    for (int n = wave; n < Nc; n += 4){
        const float* man = message_atom + ((size_t)(bs*Nc)+n)*Hc;
        float acc = 0.f;
        for (int d = lane; d < Hc; d += 64) acc = fmaf(man[d], am[d], acc);
        #pragma unroll
        for (int off = 32; off > 0; off >>= 1) acc += __shfl_xor(acc, off, 64);
        if (lane == 0) res[n] = acc * adj[((size_t)(bs*Nc)+n)*Nc + m];
    }
    __syncthreads();
    if (threadIdx.x < Nc){
        float v = res[threadIdx.x];
        float mx = v;
        #pragma unroll
        for (int off = 32; off > 0; off >>= 1) mx = fmaxf(mx, __shfl_xor(mx, off, 64));
        float e = expf(v - mx);
        float ssum = e;
        #pragma unroll
        for (int off = 32; off > 0; off >>= 1) ssum += __shfl_xor(ssum, off, 64);
        sm[((size_t)(bs*Nc)+threadIdx.x)*Nc + m] = e / ssum;
    }
}

// ---------------- K6: atom_hiddens = relu([agg|message_atom|input_atom] @ W_o + b_o)
#define R7 4
__global__ __launch_bounds__(320) void k_output(const float* __restrict__ agg,
        const float* __restrict__ message_atom, const float* __restrict__ input_atom,
        const float* __restrict__ W_o, const float* __restrict__ b_o, float* __restrict__ out){
    __shared__ float xin[R7][3*Hc];
    int r0 = blockIdx.x * R7;
    for (int idx = threadIdx.x; idx < R7*3*Hc; idx += blockDim.x){
        int r = idx / (3*Hc), k = idx - r*(3*Hc);
        int row = r0 + r;
        float v;
        if (k < Hc)           v = agg[(size_t)row*Hc + k];
        else if (k < 2*Hc)    v = message_atom[(size_t)row*Hc + (k - Hc)];
        else                  v = input_atom[(size_t)row*Hc + (k - 2*Hc)];
        xin[r][k] = v;
    }
    __syncthreads();
    int h = threadIdx.x;
    if (h < Hc){
        float acc[R7];
        #pragma unroll
        for (int r=0;r<R7;r++) acc[r] = b_o[h];
        for (int d = 0; d < 3*Hc; ++d){
            float w = W_o[d*Hc + h];
            #pragma unroll
            for (int r=0;r<R7;r++) acc[r] = fmaf(xin[r][d], w, acc[r]);
        }
        #pragma unroll
        for (int r=0;r<R7;r++) out[(size_t)(r0+r)*Hc + h] = reluf(acc[r]);
    }
}

extern "C" void kernel_launch(void* const* d_in, const int* in_sizes, int n_in,
                              void* d_out, int out_size, void* d_ws, size_t ws_size,
                              hipStream_t stream){
    const float* f_atoms  = (const float*)d_in[0];
    const float* f_bonds  = (const float*)d_in[1];
    const float* adj      = (const float*)d_in[2];
    const float* W_i_atom = (const float*)d_in[3];
    const float* W_i_bond = (const float*)d_in[4];
    const float* W_h0     = (const float*)d_in[5];
    const float* W_h1     = (const float*)d_in[6];
    const float* W_o      = (const float*)d_in[7];
    const float* b_o      = (const float*)d_in[8];

    float* out = (float*)d_out;
    float* atom_hiddens = out;                       // [2048, 300]
    float* mb_out = out + (size_t)ROWS*Hc;           // [131072, 300] fp32 (output #2)
    float* X2 = mb_out;                              // [E][160] staging, dead before mb_out's first write

    float* wsf = (float*)d_ws;
    float* input_atom   = wsf; wsf += (size_t)ROWS*Hc;          // 614400
    float* message_atom = wsf; wsf += (size_t)ROWS*Hc;
    float* sm           = wsf; wsf += (size_t)EDGES;            // 131072
    float* ib           = wsf; wsf += (size_t)EDGES*Hc;         // 39.3M floats
    unsigned short* wsu = (unsigned short*)wsf;
    unsigned short* Wt0hi = wsu; wsu += 304*320;
    unsigned short* Wt0lo = wsu; wsu += 304*320;
    unsigned short* Wt1hi = wsu; wsu += 304*320;
    unsigned short* Wt1lo = wsu; wsu += 304*320;
    unsigned short* Wtbhi = wsu; wsu += 304*160;
    unsigned short* Wtblo = wsu; wsu += 304*160;
    float* agg_out = ib;   // alias: ib dead after step-2 GEMM, agg only needed at the end

    k_atom_embed<<<ROWS, 320, 0, stream>>>(f_atoms, W_i_atom, input_atom, message_atom);
    k_prep_w<<<(304*320)/256, 256, 0, stream>>>(W_h0, Hc, 320, Wt0hi, Wt0lo);
    k_prep_w<<<(304*320)/256, 256, 0, stream>>>(W_h1, Hc, 320, Wt1hi, Wt1lo);
    k_prep_w<<<(304*160)/256, 256, 0, stream>>>(W_i_bond, BFD, 160, Wtbhi, Wtblo);
    k_bond_prep<<<(EDGES*160)/256, 256, 0, stream>>>(f_bonds, adj, X2);
    k_gemm3<0><<<EDGES/128, 512, 0, stream>>>(X2, Wtbhi, Wtblo, nullptr, nullptr, nullptr,
                                              nullptr, ib);
    // step 1: mb_old = ib -> mb_out (out-of-place; pairing grid harmless)
    k_agg<<<ROWS, 320, 0, stream>>>(ib, message_atom, nullptr, 0);
    k_resonance_softmax<<<ROWS, 256, 0, stream>>>(message_atom, adj, sm);
    k_gemm3<1><<<BS*32, 512, 0, stream>>>(ib, Wt0hi, Wt0lo, message_atom, adj, sm, ib, mb_out);
    // step 2: mb_old = mb_out -> mb_out (in-place via closed-pair blocks + barrier)
    k_agg<<<ROWS, 320, 0, stream>>>(mb_out, message_atom, nullptr, 0);
    k_resonance_softmax<<<ROWS, 256, 0, stream>>>(message_atom, adj, sm);
    k_gemm3<1><<<BS*32, 512, 0, stream>>>(mb_out, Wt1hi, Wt1lo, message_atom, adj, sm, ib, mb_out);
    // final aggregate + output layer
    k_agg<<<ROWS, 320, 0, stream>>>(mb_out, nullptr, agg_out, 1);
    k_output<<<ROWS/R7, 320, 0, stream>>>(agg_out, message_atom, input_atom, W_o, b_o, atom_hiddens);
}

// Round 4
// 907.183 us; speedup vs baseline: 2.0089x; 1.7118x over previous
//
#include <hip/hip_runtime.h>
#include <hip/hip_bf16.h>
#include <math.h>

#define Bc 8
#define Sc 4
#define Nc 64
#define AF 133
#define BFD 147
#define Hc 300
#define BS (Bc*Sc)                  // 32
#define ROWS (BS*Nc)                // 2048 atom rows
#define EDGES (BS*Nc*Nc)            // 131072 edges

typedef float f32x4 __attribute__((ext_vector_type(4)));
typedef short bf16x8 __attribute__((ext_vector_type(8)));
union U4 { uint4 u; bf16x8 v; };

__device__ __forceinline__ float reluf(float x){ return fmaxf(x, 0.f); }
__device__ __forceinline__ float b2f(unsigned short u){ union{unsigned int i;float f;}v; v.i = ((unsigned int)u)<<16; return v.f; }
__device__ __forceinline__ unsigned short f2b(float f){ __hip_bfloat16 h = __float2bfloat16(f); return *reinterpret_cast<unsigned short*>(&h); }
__device__ __forceinline__ void split2(float x, unsigned short &hi, unsigned short &lo){
    unsigned short h = f2b(x);
    float r = x - b2f(h);
    hi = h; lo = f2b(r);
}

// ---------------- K1: input_atom = relu(f_atoms @ W_i_atom); message_atom = copy (fp32 VALU)
__global__ __launch_bounds__(320) void k_atom_embed(const float* __restrict__ f_atoms,
        const float* __restrict__ W, float* __restrict__ input_atom, float* __restrict__ message_atom){
    __shared__ float x[AF];
    int row = blockIdx.x;
    const float* fr = f_atoms + (size_t)row*AF;
    for (int d = threadIdx.x; d < AF; d += blockDim.x) x[d] = fr[d];
    __syncthreads();
    int h = threadIdx.x;
    if (h < Hc){
        float acc = 0.f;
        for (int d = 0; d < AF; ++d) acc = fmaf(x[d], W[d*Hc + h], acc);
        float v = reluf(acc);
        input_atom[(size_t)row*Hc + h] = v;
        message_atom[(size_t)row*Hc + h] = v;
    }
}

// ---------------- prep: W [K][300] -> split bf16 in MFMA-fragment order
// WP[kt][ct][l][j] = W[k = kt*32 + (l>>4)*8 + j][col = ct*16 + (l&15)]  (0-padded)
__global__ __launch_bounds__(256) void k_prep_wp(const float* __restrict__ W, int K, int NKT,
        unsigned short* __restrict__ WPhi, unsigned short* __restrict__ WPlo){
    int idx = blockIdx.x*256 + threadIdx.x;
    if (idx >= NKT*19*64*8) return;
    int j  = idx & 7;
    int l  = (idx >> 3) & 63;
    int ct = (idx >> 9) % 19;
    int kt = idx / (19*64*8);
    int col = ct*16 + (l & 15);
    int k   = kt*32 + (l >> 4)*8 + j;
    float v = (col < Hc && k < K) ? W[k*Hc + col] : 0.f;
    unsigned short hi, lo; split2(v, hi, lo);
    WPhi[idx] = hi; WPlo[idx] = lo;
}

// ---------------- prep: X2[e][k] = adj[e]*f_bonds[e][k] fp32, zero-padded to K=160
__global__ __launch_bounds__(256) void k_bond_prep(const float* __restrict__ f_bonds,
        const float* __restrict__ adj, float* __restrict__ X2){
    int idx = blockIdx.x*256 + threadIdx.x;   // over EDGES*160
    int e = idx / 160, k = idx - e*160;
    X2[idx] = (k < BFD) ? adj[e]*f_bonds[(size_t)e*BFD + k] : 0.f;
}

// ---------------- tiled split-bf16 MFMA edge GEMM (128 rows x 304 cols per block)
// MODE 0: dst = relu(X2 @ W_i_bond)                 (plain row blocks, 1024 blocks)
// MODE 1: dst[eo] = relu(ib[eo] + A @ W_h)*sm[eo]   (closed-pair blocks; in-place safe)
//         A-row for output edge (a,b): adj[(b,a)]*ma[a,:] - mb_old[(b,a),:]
template<int MODE>
__global__ __launch_bounds__(1024) void k_gemm_t(
        const float* __restrict__ Asrc,          // MODE0: X2 [E][160]; MODE1: mb_old [E][300]
        const unsigned short* __restrict__ WPhi, // fragment-ordered [NKT][19][64][8]
        const unsigned short* __restrict__ WPlo,
        const float* __restrict__ ma,
        const float* __restrict__ adj,
        const float* __restrict__ sm,
        const float* __restrict__ ib,
        float* __restrict__ dst)
{
    constexpr int NKT  = MODE ? 10 : 5;
    constexpr int ASTR = MODE ? 300 : 160;

    __shared__ unsigned short sA[2][2][4096];    // [buf][hi/lo][512 chunks x 8]
    __shared__ int s_eOut[128];
    __shared__ int s_eRev[128];
    __shared__ float s_adjRev[128];
    __shared__ int s_aAtom[128];

    const int t = threadIdx.x;
    if (MODE){
        if (t < 128){
            int r = t;
            int bs = blockIdx.x >> 5, kk = blockIdx.x & 31;
            int s1 = 64-kk, s2 = 127-2*kk, s3 = 128-kk;
            int a, b;
            if (r < s1){ a = kk; b = kk + r; }
            else if (r < s2){ a = kk+1 + (r - s1); b = kk; }
            else if (r < s3){ a = 63-kk; b = 63-kk + (r - s2); }
            else { a = 64-kk + (r - s3); b = 63-kk; }
            int eo = (bs*64 + a)*64 + b;
            int er = (bs*64 + b)*64 + a;
            s_eOut[r] = eo; s_eRev[r] = er; s_aAtom[r] = bs*64 + a;
            s_adjRev[r] = adj[er];
        }
        __syncthreads();
    }

    // ---- A-build role: thread t handles row br, k-offset jb..jb+3 within each 32-k tile
    const int br = t >> 3;
    const int jb = (t & 7) * 4;
    const float* aRow;
    const float* mRow = nullptr;
    float adjR = 0.f;
    if (MODE){
        aRow = Asrc + (size_t)s_eRev[br]*ASTR;
        mRow = ma + (size_t)s_aAtom[br]*Hc;
        adjR = s_adjRev[br];
    } else {
        aRow = Asrc + (size_t)(blockIdx.x*128 + br)*ASTR;
    }
    const int chunk = (br>>4)*64 + (br&15) + 16*(jb>>3);
    const int ldsOff = chunk*8 + (jb&7);         // shorts; 8B-aligned

    float4 pm, pa;
    auto issueLoad = [&](int kt){
        int k0 = kt*32 + jb;
        if (!MODE){
            pm = *(const float4*)(aRow + k0);                 // padded to 160
        } else if (k0 <= 296){
            pm = *(const float4*)(aRow + k0);
            pa = *(const float4*)(mRow + k0);
        }
    };
    auto buildA = [&](int kt, int buf){
        int k0 = kt*32 + jb;
        float xv[4];
        if (!MODE){
            xv[0]=pm.x; xv[1]=pm.y; xv[2]=pm.z; xv[3]=pm.w;
        } else if (k0 <= 296){
            xv[0]=fmaf(adjR,pa.x,-pm.x); xv[1]=fmaf(adjR,pa.y,-pm.y);
            xv[2]=fmaf(adjR,pa.z,-pm.z); xv[3]=fmaf(adjR,pa.w,-pm.w);
        } else { xv[0]=xv[1]=xv[2]=xv[3]=0.f; }
        unsigned short h0,l0,h1,l1,h2,l2,h3,l3;
        split2(xv[0],h0,l0); split2(xv[1],h1,l1);
        split2(xv[2],h2,l2); split2(xv[3],h3,l3);
        uint2 hw, lw;
        hw.x = (unsigned int)h0 | ((unsigned int)h1<<16);
        hw.y = (unsigned int)h2 | ((unsigned int)h3<<16);
        lw.x = (unsigned int)l0 | ((unsigned int)l1<<16);
        lw.y = (unsigned int)l2 | ((unsigned int)l3<<16);
        *(uint2*)&sA[buf][0][ldsOff] = hw;
        *(uint2*)&sA[buf][1][ldsOff] = lw;
    };

    // ---- compute role
    const int wv = t >> 6, lane = t & 63;
    const int li = lane & 15, quad = lane >> 4;
    const int rg = wv & 3;                       // row-tiles 2rg, 2rg+1
    const int cg = wv >> 2;                      // col group
    const int c0 = cg*5;
    const int myC = (cg < 3) ? 5 : 4;

    f32x4 acc[5][2];
    #pragma unroll
    for (int c = 0; c < 5; ++c){ acc[c][0] = (f32x4){0,0,0,0}; acc[c][1] = (f32x4){0,0,0,0}; }

    issueLoad(0);
    buildA(0, 0);
    __syncthreads();

    for (int kt = 0; kt < NKT; ++kt){
        int buf = kt & 1;
        if (kt+1 < NKT) issueLoad(kt+1);
        U4 a0h, a0l, a1h, a1l;
        a0h.u = *(const uint4*)&sA[buf][0][((2*rg  )*64 + lane)*8];
        a0l.u = *(const uint4*)&sA[buf][1][((2*rg  )*64 + lane)*8];
        a1h.u = *(const uint4*)&sA[buf][0][((2*rg+1)*64 + lane)*8];
        a1l.u = *(const uint4*)&sA[buf][1][((2*rg+1)*64 + lane)*8];
        const unsigned short* wh = WPhi + (size_t)kt*(19*64*8) + lane*8;
        const unsigned short* wl = WPlo + (size_t)kt*(19*64*8) + lane*8;
        #pragma unroll
        for (int c = 0; c < 5; ++c){
            if (c < myC){
                U4 bh, bl;
                bh.u = *(const uint4*)(wh + (size_t)(c0+c)*512);
                bl.u = *(const uint4*)(wl + (size_t)(c0+c)*512);
                acc[c][0] = __builtin_amdgcn_mfma_f32_16x16x32_bf16(a0h.v, bl.v, acc[c][0], 0,0,0);
                acc[c][0] = __builtin_amdgcn_mfma_f32_16x16x32_bf16(a0l.v, bh.v, acc[c][0], 0,0,0);
                acc[c][0] = __builtin_amdgcn_mfma_f32_16x16x32_bf16(a0h.v, bh.v, acc[c][0], 0,0,0);
                acc[c][1] = __builtin_amdgcn_mfma_f32_16x16x32_bf16(a1h.v, bl.v, acc[c][1], 0,0,0);
                acc[c][1] = __builtin_amdgcn_mfma_f32_16x16x32_bf16(a1l.v, bh.v, acc[c][1], 0,0,0);
                acc[c][1] = __builtin_amdgcn_mfma_f32_16x16x32_bf16(a1h.v, bh.v, acc[c][1], 0,0,0);
            }
        }
        if (kt+1 < NKT) buildA(kt+1, buf^1);
        __syncthreads();
    }

    // ---- epilogue (after last barrier: all in-place reads have completed)
    int eO[2][4]; float smv[2][4];
    #pragma unroll
    for (int r2 = 0; r2 < 2; ++r2)
        #pragma unroll
        for (int i = 0; i < 4; ++i){
            int row = (2*rg + r2)*16 + quad*4 + i;
            int e = MODE ? s_eOut[row] : blockIdx.x*128 + row;
            eO[r2][i] = e;
            if (MODE) smv[r2][i] = sm[e];
        }
    #pragma unroll
    for (int c = 0; c < 5; ++c){
        if (c >= myC) continue;
        int h = (c0 + c)*16 + li;
        if (h >= Hc) continue;
        #pragma unroll
        for (int r2 = 0; r2 < 2; ++r2)
            #pragma unroll
            for (int i = 0; i < 4; ++i){
                size_t off = (size_t)eO[r2][i]*Hc + h;
                float v = acc[c][r2][i];
                if (MODE) v = reluf(v + ib[off]) * smv[r2][i];
                else      v = reluf(v);
                dst[off] = v;
            }
    }
}

// ---------------- K3: agg[bs,m,h] = (sum_n mb[n,m,h]) * sigmoid(max_n mb[n,m,h])  (fp32)
__global__ __launch_bounds__(320) void k_agg(const float* __restrict__ message_bond,
        float* __restrict__ message_atom, float* __restrict__ agg_out, int final_mode){
    int row = blockIdx.x;           // bs*64 + m
    int bs = row >> 6, m = row & 63;
    int h = threadIdx.x;
    if (h >= Hc) return;
    size_t base = ((size_t)(bs*Nc)*Nc + m)*(size_t)Hc + h;
    float s = 0.f, mx = -INFINITY;
    for (int n = 0; n < Nc; ++n){
        float v = message_bond[base + (size_t)n*Nc*Hc];
        s += v; mx = fmaxf(mx, v);
    }
    float agg = s * (1.f/(1.f + expf(-mx)));
    if (final_mode) agg_out[(size_t)row*Hc + h] = agg;
    else message_atom[(size_t)row*Hc + h] += agg;
}

// ---------------- K4: res[n,m] = dot(ma[n],ma[m])*adj[n,m]; sm = softmax over n per (b,s,m)
__global__ __launch_bounds__(256) void k_resonance_softmax(const float* __restrict__ message_atom,
        const float* __restrict__ adj, float* __restrict__ sm){
    int bs = blockIdx.x >> 6, m = blockIdx.x & 63;
    __shared__ float am[Hc];
    __shared__ float res[Nc];
    for (int d = threadIdx.x; d < Hc; d += blockDim.x)
        am[d] = message_atom[((size_t)(bs*Nc)+m)*Hc + d];
    __syncthreads();
    int wave = threadIdx.x >> 6, lane = threadIdx.x & 63;
    for (int n = wave; n < Nc; n += 4){
        const float* man = message_atom + ((size_t)(bs*Nc)+n)*Hc;
        float acc = 0.f;
        for (int d = lane; d < Hc; d += 64) acc = fmaf(man[d], am[d], acc);
        #pragma unroll
        for (int off = 32; off > 0; off >>= 1) acc += __shfl_xor(acc, off, 64);
        if (lane == 0) res[n] = acc * adj[((size_t)(bs*Nc)+n)*Nc + m];
    }
    __syncthreads();
    if (threadIdx.x < Nc){
        float v = res[threadIdx.x];
        float mx = v;
        #pragma unroll
        for (int off = 32; off > 0; off >>= 1) mx = fmaxf(mx, __shfl_xor(mx, off, 64));
        float e = expf(v - mx);
        float ssum = e;
        #pragma unroll
        for (int off = 32; off > 0; off >>= 1) ssum += __shfl_xor(ssum, off, 64);
        sm[((size_t)(bs*Nc)+threadIdx.x)*Nc + m] = e / ssum;
    }
}

// ---------------- K6: atom_hiddens = relu([agg|message_atom|input_atom] @ W_o + b_o)
#define R7 4
__global__ __launch_bounds__(320) void k_output(const float* __restrict__ agg,
        const float* __restrict__ message_atom, const float* __restrict__ input_atom,
        const float* __restrict__ W_o, const float* __restrict__ b_o, float* __restrict__ out){
    __shared__ float xin[R7][3*Hc];
    int r0 = blockIdx.x * R7;
    for (int idx = threadIdx.x; idx < R7*3*Hc; idx += blockDim.x){
        int r = idx / (3*Hc), k = idx - r*(3*Hc);
        int row = r0 + r;
        float v;
        if (k < Hc)           v = agg[(size_t)row*Hc + k];
        else if (k < 2*Hc)    v = message_atom[(size_t)row*Hc + (k - Hc)];
        else                  v = input_atom[(size_t)row*Hc + (k - 2*Hc)];
        xin[r][k] = v;
    }
    __syncthreads();
    int h = threadIdx.x;
    if (h < Hc){
        float acc[R7];
        #pragma unroll
        for (int r=0;r<R7;r++) acc[r] = b_o[h];
        for (int d = 0; d < 3*Hc; ++d){
            float w = W_o[d*Hc + h];
            #pragma unroll
            for (int r=0;r<R7;r++) acc[r] = fmaf(xin[r][d], w, acc[r]);
        }
        #pragma unroll
        for (int r=0;r<R7;r++) out[(size_t)(r0+r)*Hc + h] = reluf(acc[r]);
    }
}

extern "C" void kernel_launch(void* const* d_in, const int* in_sizes, int n_in,
                              void* d_out, int out_size, void* d_ws, size_t ws_size,
                              hipStream_t stream){
    const float* f_atoms  = (const float*)d_in[0];
    const float* f_bonds  = (const float*)d_in[1];
    const float* adj      = (const float*)d_in[2];
    const float* W_i_atom = (const float*)d_in[3];
    const float* W_i_bond = (const float*)d_in[4];
    const float* W_h0     = (const float*)d_in[5];
    const float* W_h1     = (const float*)d_in[6];
    const float* W_o      = (const float*)d_in[7];
    const float* b_o      = (const float*)d_in[8];

    float* out = (float*)d_out;
    float* atom_hiddens = out;                       // [2048, 300]
    float* mb_out = out + (size_t)ROWS*Hc;           // [131072, 300] fp32 (output #2)
    float* X2 = mb_out;                              // [E][160] staging, dead before mb_out written

    float* wsf = (float*)d_ws;
    float* input_atom   = wsf; wsf += (size_t)ROWS*Hc;
    float* message_atom = wsf; wsf += (size_t)ROWS*Hc;
    float* sm           = wsf; wsf += (size_t)EDGES;
    float* ib           = wsf; wsf += (size_t)EDGES*Hc;         // 39.3M floats
    unsigned short* wsu = (unsigned short*)wsf;
    unsigned short* WP0hi = wsu; wsu += 10*19*64*8;
    unsigned short* WP0lo = wsu; wsu += 10*19*64*8;
    unsigned short* WP1hi = wsu; wsu += 10*19*64*8;
    unsigned short* WP1lo = wsu; wsu += 10*19*64*8;
    unsigned short* WPbhi = wsu; wsu += 5*19*64*8;
    unsigned short* WPblo = wsu; wsu += 5*19*64*8;
    float* agg_out = ib;   // alias: ib dead after step-2 GEMM

    k_atom_embed<<<ROWS, 320, 0, stream>>>(f_atoms, W_i_atom, input_atom, message_atom);
    k_prep_wp<<<(10*19*64*8)/256, 256, 0, stream>>>(W_h0, Hc, 10, WP0hi, WP0lo);
    k_prep_wp<<<(10*19*64*8)/256, 256, 0, stream>>>(W_h1, Hc, 10, WP1hi, WP1lo);
    k_prep_wp<<<(5*19*64*8)/256, 256, 0, stream>>>(W_i_bond, BFD, 5, WPbhi, WPblo);
    k_bond_prep<<<(EDGES*160)/256, 256, 0, stream>>>(f_bonds, adj, X2);
    k_gemm_t<0><<<EDGES/128, 1024, 0, stream>>>(X2, WPbhi, WPblo, nullptr, nullptr, nullptr,
                                                nullptr, ib);
    // step 1: mb_old = ib -> mb_out (out-of-place)
    k_agg<<<ROWS, 320, 0, stream>>>(ib, message_atom, nullptr, 0);
    k_resonance_softmax<<<ROWS, 256, 0, stream>>>(message_atom, adj, sm);
    k_gemm_t<1><<<BS*32, 1024, 0, stream>>>(ib, WP0hi, WP0lo, message_atom, adj, sm, ib, mb_out);
    // step 2: mb_old = mb_out -> mb_out (in-place via closed-pair blocks)
    k_agg<<<ROWS, 320, 0, stream>>>(mb_out, message_atom, nullptr, 0);
    k_resonance_softmax<<<ROWS, 256, 0, stream>>>(message_atom, adj, sm);
    k_gemm_t<1><<<BS*32, 1024, 0, stream>>>(mb_out, WP1hi, WP1lo, message_atom, adj, sm, ib, mb_out);
    // final aggregate + output layer
    k_agg<<<ROWS, 320, 0, stream>>>(mb_out, nullptr, agg_out, 1);
    k_output<<<ROWS/R7, 320, 0, stream>>>(agg_out, message_atom, input_atom, W_o, b_o, atom_hiddens);
}

// Round 5
// 822.101 us; speedup vs baseline: 2.2169x; 1.1035x over previous
//
#include <hip/hip_runtime.h>
#include <hip/hip_bf16.h>
#include <math.h>

#define Bc 8
#define Sc 4
#define Nc 64
#define AF 133
#define BFD 147
#define Hc 300
#define BS (Bc*Sc)                  // 32
#define ROWS (BS*Nc)                // 2048 atom rows
#define EDGES (BS*Nc*Nc)            // 131072 edges
#define BSLICE 19456                // shorts per kt-slice of WP: 2*19*64*8
#define BHALF  9728                 // 19*64*8

typedef float f32x4 __attribute__((ext_vector_type(4)));
typedef short bf16x8 __attribute__((ext_vector_type(8)));
union U4 { uint4 u; bf16x8 v; };

__device__ __forceinline__ float reluf(float x){ return fmaxf(x, 0.f); }
__device__ __forceinline__ float b2f(unsigned short u){ union{unsigned int i;float f;}v; v.i = ((unsigned int)u)<<16; return v.f; }
__device__ __forceinline__ unsigned short f2b(float f){ __hip_bfloat16 h = __float2bfloat16(f); return *reinterpret_cast<unsigned short*>(&h); }
__device__ __forceinline__ void split2(float x, unsigned short &hi, unsigned short &lo){
    unsigned short h = f2b(x);
    float r = x - b2f(h);
    hi = h; lo = f2b(r);
}

// ---------------- K1: input_atom = relu(f_atoms @ W_i_atom); message_atom = copy (fp32 VALU)
__global__ __launch_bounds__(320) void k_atom_embed(const float* __restrict__ f_atoms,
        const float* __restrict__ W, float* __restrict__ input_atom, float* __restrict__ message_atom){
    __shared__ float x[AF];
    int row = blockIdx.x;
    const float* fr = f_atoms + (size_t)row*AF;
    for (int d = threadIdx.x; d < AF; d += blockDim.x) x[d] = fr[d];
    __syncthreads();
    int h = threadIdx.x;
    if (h < Hc){
        float acc = 0.f;
        for (int d = 0; d < AF; ++d) acc = fmaf(x[d], W[d*Hc + h], acc);
        float v = reluf(acc);
        input_atom[(size_t)row*Hc + h] = v;
        message_atom[(size_t)row*Hc + h] = v;
    }
}

// ---------------- prep: W [K][300] -> split bf16, layout [kt][hi/lo][19 ct][64 lane][8]
__global__ __launch_bounds__(256) void k_prep_wp2(const float* __restrict__ W, int K, int NKT,
        unsigned short* __restrict__ WP){
    int idx = blockIdx.x*256 + threadIdx.x;
    if (idx >= NKT*BSLICE) return;
    int j  = idx & 7;
    int l  = (idx >> 3) & 63;
    int ct = (idx >> 9) % 19;
    int rem = idx / BHALF;
    int hl = rem & 1;
    int kt = rem >> 1;
    int col = ct*16 + (l & 15);
    int k   = kt*32 + (l >> 4)*8 + j;
    float v = (col < Hc && k < K) ? W[k*Hc + col] : 0.f;
    unsigned short hi, lo; split2(v, hi, lo);
    WP[idx] = hl ? lo : hi;
}

// ---------------- tiled split-bf16 MFMA edge GEMM (128 rows x 304 cols per block)
// MODE 0: dst = relu((adj*f_bonds) @ W_i_bond)      (plain row blocks, K=147 pad 160)
// MODE 1: dst[eo] = relu(ib[eo] + A @ W_h)*sm[eo]   (closed-pair blocks; in-place safe)
//         A-row for output edge (a,b): adj[(b,a)]*ma[a,:] - mb_old[(b,a),:]
// B staged per-kt through LDS (fragment-ordered); sA producer writes are bank-linear.
template<int MODE>
__global__ __launch_bounds__(1024) void k_gemm_t(
        const float* __restrict__ Asrc,          // MODE0: f_bonds [E][147]; MODE1: mb_old [E][300]
        const unsigned short* __restrict__ WP,   // [NKT][2][19][64][8]
        const float* __restrict__ ma,
        const float* __restrict__ adj,
        const float* __restrict__ sm,
        const float* __restrict__ ib,
        float* __restrict__ dst)
{
    constexpr int NKT  = MODE ? 10 : 5;
    constexpr int ASTR = MODE ? 300 : BFD;

    __shared__ unsigned short sAhi[4096];        // 128 rows x 32 k (chunked)
    __shared__ unsigned short sAlo[4096];
    __shared__ unsigned short sB[BSLICE];        // hi block then lo block
    __shared__ int s_eOut[128];
    __shared__ int s_eRev[128];
    __shared__ float s_adjRev[128];
    __shared__ int s_aAtom[128];

    const int t = threadIdx.x;
    if (MODE){
        if (t < 128){
            int r = t;
            int bs = blockIdx.x >> 5, kk = blockIdx.x & 31;
            int s1 = 64-kk, s2 = 127-2*kk, s3 = 128-kk;
            int a, b;
            if (r < s1){ a = kk; b = kk + r; }
            else if (r < s2){ a = kk+1 + (r - s1); b = kk; }
            else if (r < s3){ a = 63-kk; b = 63-kk + (r - s2); }
            else { a = 64-kk + (r - s3); b = 63-kk; }
            int eo = (bs*64 + a)*64 + b;
            int er = (bs*64 + b)*64 + a;
            s_eOut[r] = eo; s_eRev[r] = er; s_aAtom[r] = bs*64 + a;
            s_adjRev[r] = adj[er];
        }
        __syncthreads();
    }

    // ---- A-build role: thread t -> row brow, k-offset koff (4 floats), LDS shorts [4t..4t+3]
    const int rt_b = t >> 7;
    const int q_b  = (t >> 5) & 3;
    const int li_b = (t >> 1) & 15;
    const int half = t & 1;
    const int brow = rt_b*16 + li_b;
    const int koff = q_b*8 + 4*half;
    const float* aRow;
    const float* mRow = nullptr;
    float adjR = 0.f;
    if (MODE){
        aRow = Asrc + (size_t)s_eRev[brow]*ASTR;
        mRow = ma + (size_t)s_aAtom[brow]*Hc;
        adjR = s_adjRev[brow];
    } else {
        int e = blockIdx.x*128 + brow;
        aRow = Asrc + (size_t)e*ASTR;
        adjR = adj[e];
    }

    float pm[4], pa[4];
    auto prefetchA = [&](int kt){
        int k0 = kt*32 + koff;
        if (MODE){
            if (k0 <= 296){
                float4 v = *(const float4*)(aRow + k0);
                float4 w = *(const float4*)(mRow + k0);
                pm[0]=v.x; pm[1]=v.y; pm[2]=v.z; pm[3]=v.w;
                pa[0]=w.x; pa[1]=w.y; pa[2]=w.z; pa[3]=w.w;
            }
        } else {
            #pragma unroll
            for (int j = 0; j < 4; ++j){
                int k = k0 + j;
                pm[j] = (k < BFD) ? aRow[k] : 0.f;
            }
        }
    };
    auto buildA = [&](int kt){
        int k0 = kt*32 + koff;
        float xv[4];
        if (MODE){
            if (k0 <= 296){
                #pragma unroll
                for (int j = 0; j < 4; ++j) xv[j] = fmaf(adjR, pa[j], -pm[j]);
            } else { xv[0]=xv[1]=xv[2]=xv[3]=0.f; }
        } else {
            #pragma unroll
            for (int j = 0; j < 4; ++j) xv[j] = adjR * pm[j];
        }
        unsigned short h0,l0,h1,l1,h2,l2,h3,l3;
        split2(xv[0],h0,l0); split2(xv[1],h1,l1);
        split2(xv[2],h2,l2); split2(xv[3],h3,l3);
        uint2 hw, lw;
        hw.x = (unsigned int)h0 | ((unsigned int)h1<<16);
        hw.y = (unsigned int)h2 | ((unsigned int)h3<<16);
        lw.x = (unsigned int)l0 | ((unsigned int)l1<<16);
        lw.y = (unsigned int)l2 | ((unsigned int)l3<<16);
        *(uint2*)&sAhi[4*t] = hw;        // byte 8t: bank-linear, conflict-free
        *(uint2*)&sAlo[4*t] = lw;
    };
    auto copyB = [&](int kt){
        const unsigned short* src = WP + (size_t)kt*BSLICE;
        #pragma unroll
        for (int rep = 0; rep < 3; ++rep){
            int i = t + rep*1024;
            if (i < BSLICE/8){
                uint4 v = *(const uint4*)(src + i*8);
                *(uint4*)&sB[i*8] = v;
            }
        }
    };

    // ---- compute role
    const int wv = t >> 6, lane = t & 63;
    const int li = lane & 15, quad = lane >> 4;
    const int rg = wv & 3;                       // row-tiles 2rg, 2rg+1
    const int cg = wv >> 2;
    const int c0 = cg*5;
    const int myC = (cg < 3) ? 5 : 4;

    f32x4 acc[5][2];
    #pragma unroll
    for (int c = 0; c < 5; ++c){ acc[c][0] = (f32x4){0,0,0,0}; acc[c][1] = (f32x4){0,0,0,0}; }

    prefetchA(0);
    for (int kt = 0; kt < NKT; ++kt){
        if (kt) __syncthreads();                 // B1: readers of kt-1 done
        copyB(kt);
        buildA(kt);
        __syncthreads();                         // B2: sA/sB(kt) visible
        if (kt+1 < NKT) prefetchA(kt+1);         // drains at next B1 (absorbed by compute)
        U4 a0h, a0l, a1h, a1l;
        a0h.u = *(const uint4*)&sAhi[((2*rg  )*64 + lane)*8];
        a0l.u = *(const uint4*)&sAlo[((2*rg  )*64 + lane)*8];
        a1h.u = *(const uint4*)&sAhi[((2*rg+1)*64 + lane)*8];
        a1l.u = *(const uint4*)&sAlo[((2*rg+1)*64 + lane)*8];
        #pragma unroll
        for (int c = 0; c < 5; ++c){
            if (c < myC){
                U4 bh, bl;
                bh.u = *(const uint4*)&sB[        (c0+c)*512 + lane*8];
                bl.u = *(const uint4*)&sB[BHALF + (c0+c)*512 + lane*8];
                acc[c][0] = __builtin_amdgcn_mfma_f32_16x16x32_bf16(a0h.v, bl.v, acc[c][0], 0,0,0);
                acc[c][0] = __builtin_amdgcn_mfma_f32_16x16x32_bf16(a0l.v, bh.v, acc[c][0], 0,0,0);
                acc[c][0] = __builtin_amdgcn_mfma_f32_16x16x32_bf16(a0h.v, bh.v, acc[c][0], 0,0,0);
                acc[c][1] = __builtin_amdgcn_mfma_f32_16x16x32_bf16(a1h.v, bl.v, acc[c][1], 0,0,0);
                acc[c][1] = __builtin_amdgcn_mfma_f32_16x16x32_bf16(a1l.v, bh.v, acc[c][1], 0,0,0);
                acc[c][1] = __builtin_amdgcn_mfma_f32_16x16x32_bf16(a1h.v, bh.v, acc[c][1], 0,0,0);
            }
        }
    }

    // ---- epilogue (in-place safe: all global A-reads were consumed before last B2)
    int eO[2][4]; float smv[2][4];
    #pragma unroll
    for (int r2 = 0; r2 < 2; ++r2)
        #pragma unroll
        for (int i = 0; i < 4; ++i){
            int row = (2*rg + r2)*16 + quad*4 + i;
            int e = MODE ? s_eOut[row] : blockIdx.x*128 + row;
            eO[r2][i] = e;
            if (MODE) smv[r2][i] = sm[e];
        }
    #pragma unroll
    for (int c = 0; c < 5; ++c){
        if (c >= myC) continue;
        int h = (c0 + c)*16 + li;
        if (h >= Hc) continue;
        #pragma unroll
        for (int r2 = 0; r2 < 2; ++r2)
            #pragma unroll
            for (int i = 0; i < 4; ++i){
                size_t off = (size_t)eO[r2][i]*Hc + h;
                float v = acc[c][r2][i];
                if (MODE) v = reluf(v + ib[off]) * smv[r2][i];
                else      v = reluf(v);
                dst[off] = v;
            }
    }
}

// ---------------- K3: agg[bs,m,h] = (sum_n mb[n,m,h]) * sigmoid(max_n mb[n,m,h])  (fp32)
__global__ __launch_bounds__(320) void k_agg(const float* __restrict__ message_bond,
        float* __restrict__ message_atom, float* __restrict__ agg_out, int final_mode){
    int row = blockIdx.x;           // bs*64 + m
    int bs = row >> 6, m = row & 63;
    int h = threadIdx.x;
    if (h >= Hc) return;
    size_t base = ((size_t)(bs*Nc)*Nc + m)*(size_t)Hc + h;
    float s = 0.f, mx = -INFINITY;
    for (int n = 0; n < Nc; ++n){
        float v = message_bond[base + (size_t)n*Nc*Hc];
        s += v; mx = fmaxf(mx, v);
    }
    float agg = s * (1.f/(1.f + expf(-mx)));
    if (final_mode) agg_out[(size_t)row*Hc + h] = agg;
    else message_atom[(size_t)row*Hc + h] += agg;
}

// ---------------- K4: res[n,m] = dot(ma[n],ma[m])*adj[n,m]; sm = softmax over n per (b,s,m)
__global__ __launch_bounds__(256) void k_resonance_softmax(const float* __restrict__ message_atom,
        const float* __restrict__ adj, float* __restrict__ sm){
    int bs = blockIdx.x >> 6, m = blockIdx.x & 63;
    __shared__ float am[Hc];
    __shared__ float res[Nc];
    for (int d = threadIdx.x; d < Hc; d += blockDim.x)
        am[d] = message_atom[((size_t)(bs*Nc)+m)*Hc + d];
    __syncthreads();
    int wave = threadIdx.x >> 6, lane = threadIdx.x & 63;
    for (int n = wave; n < Nc; n += 4){
        const float* man = message_atom + ((size_t)(bs*Nc)+n)*Hc;
        float acc = 0.f;
        for (int d = lane; d < Hc; d += 64) acc = fmaf(man[d], am[d], acc);
        #pragma unroll
        for (int off = 32; off > 0; off >>= 1) acc += __shfl_xor(acc, off, 64);
        if (lane == 0) res[n] = acc * adj[((size_t)(bs*Nc)+n)*Nc + m];
    }
    __syncthreads();
    if (threadIdx.x < Nc){
        float v = res[threadIdx.x];
        float mx = v;
        #pragma unroll
        for (int off = 32; off > 0; off >>= 1) mx = fmaxf(mx, __shfl_xor(mx, off, 64));
        float e = expf(v - mx);
        float ssum = e;
        #pragma unroll
        for (int off = 32; off > 0; off >>= 1) ssum += __shfl_xor(ssum, off, 64);
        sm[((size_t)(bs*Nc)+threadIdx.x)*Nc + m] = e / ssum;
    }
}

// ---------------- K6: atom_hiddens = relu([agg|message_atom|input_atom] @ W_o + b_o)
#define R7 4
__global__ __launch_bounds__(320) void k_output(const float* __restrict__ agg,
        const float* __restrict__ message_atom, const float* __restrict__ input_atom,
        const float* __restrict__ W_o, const float* __restrict__ b_o, float* __restrict__ out){
    __shared__ float xin[R7][3*Hc];
    int r0 = blockIdx.x * R7;
    for (int idx = threadIdx.x; idx < R7*3*Hc; idx += blockDim.x){
        int r = idx / (3*Hc), k = idx - r*(3*Hc);
        int row = r0 + r;
        float v;
        if (k < Hc)           v = agg[(size_t)row*Hc + k];
        else if (k < 2*Hc)    v = message_atom[(size_t)row*Hc + (k - Hc)];
        else                  v = input_atom[(size_t)row*Hc + (k - 2*Hc)];
        xin[r][k] = v;
    }
    __syncthreads();
    int h = threadIdx.x;
    if (h < Hc){
        float acc[R7];
        #pragma unroll
        for (int r=0;r<R7;r++) acc[r] = b_o[h];
        for (int d = 0; d < 3*Hc; ++d){
            float w = W_o[d*Hc + h];
            #pragma unroll
            for (int r=0;r<R7;r++) acc[r] = fmaf(xin[r][d], w, acc[r]);
        }
        #pragma unroll
        for (int r=0;r<R7;r++) out[(size_t)(r0+r)*Hc + h] = reluf(acc[r]);
    }
}

extern "C" void kernel_launch(void* const* d_in, const int* in_sizes, int n_in,
                              void* d_out, int out_size, void* d_ws, size_t ws_size,
                              hipStream_t stream){
    const float* f_atoms  = (const float*)d_in[0];
    const float* f_bonds  = (const float*)d_in[1];
    const float* adj      = (const float*)d_in[2];
    const float* W_i_atom = (const float*)d_in[3];
    const float* W_i_bond = (const float*)d_in[4];
    const float* W_h0     = (const float*)d_in[5];
    const float* W_h1     = (const float*)d_in[6];
    const float* W_o      = (const float*)d_in[7];
    const float* b_o      = (const float*)d_in[8];

    float* out = (float*)d_out;
    float* atom_hiddens = out;                       // [2048, 300]
    float* mb_out = out + (size_t)ROWS*Hc;           // [131072, 300] fp32 (output #2)

    float* wsf = (float*)d_ws;
    float* input_atom   = wsf; wsf += (size_t)ROWS*Hc;
    float* message_atom = wsf; wsf += (size_t)ROWS*Hc;
    float* sm           = wsf; wsf += (size_t)EDGES;
    float* ib           = wsf; wsf += (size_t)EDGES*Hc;         // 39.3M floats
    unsigned short* wsu = (unsigned short*)wsf;
    unsigned short* WP0 = wsu; wsu += 10*BSLICE;
    unsigned short* WP1 = wsu; wsu += 10*BSLICE;
    unsigned short* WPb = wsu; wsu += 5*BSLICE;
    float* agg_out = ib;   // alias: ib dead after step-2 GEMM

    k_atom_embed<<<ROWS, 320, 0, stream>>>(f_atoms, W_i_atom, input_atom, message_atom);
    k_prep_wp2<<<(10*BSLICE + 255)/256, 256, 0, stream>>>(W_h0, Hc, 10, WP0);
    k_prep_wp2<<<(10*BSLICE + 255)/256, 256, 0, stream>>>(W_h1, Hc, 10, WP1);
    k_prep_wp2<<<(5*BSLICE + 255)/256, 256, 0, stream>>>(W_i_bond, BFD, 5, WPb);
    // bond embed (fused adj*f_bonds): ib = relu((adj*f_bonds) @ W_i_bond)
    k_gemm_t<0><<<EDGES/128, 1024, 0, stream>>>(f_bonds, WPb, nullptr, adj, nullptr, nullptr, ib);
    // step 1: mb_old = ib -> mb_out (out-of-place)
    k_agg<<<ROWS, 320, 0, stream>>>(ib, message_atom, nullptr, 0);
    k_resonance_softmax<<<ROWS, 256, 0, stream>>>(message_atom, adj, sm);
    k_gemm_t<1><<<BS*32, 1024, 0, stream>>>(ib, WP0, message_atom, adj, sm, ib, mb_out);
    // step 2: mb_old = mb_out -> mb_out (in-place via closed-pair blocks)
    k_agg<<<ROWS, 320, 0, stream>>>(mb_out, message_atom, nullptr, 0);
    k_resonance_softmax<<<ROWS, 256, 0, stream>>>(message_atom, adj, sm);
    k_gemm_t<1><<<BS*32, 1024, 0, stream>>>(mb_out, WP1, message_atom, adj, sm, ib, mb_out);
    // final aggregate + output layer
    k_agg<<<ROWS, 320, 0, stream>>>(mb_out, nullptr, agg_out, 1);
    k_output<<<ROWS/R7, 320, 0, stream>>>(agg_out, message_atom, input_atom, W_o, b_o, atom_hiddens);
}